// Round 2
// 498.189 us; speedup vs baseline: 1.0743x; 1.0743x over previous
//
#include <hip/hip_runtime.h>

#define NCH    64
#define NPTS   16384
#define NS     16
#define QSCALE 0.125f

// v3: single-pass streaming rewrite. (Resubmit — round-1 bench was an infra
// failure: "MI355X container failed twice", no compile/correctness verdict.)
//
// Previous version (161us kernel): grid=1024 = ONE generation at 4 blocks/CU,
// barrier-lockstepped phases (VALUBusy 9.5%, HBM 23% -> latency/serialization
// bound), and cost streamed twice (HBM + L3).
//
// This version: each wave owns 4 points and holds that cost tile
// (4n x 64c x 16s = 16KB = 64 VGPR/lane) in registers. Lane = (c2:2|n:2|s4:2).
// Logits, softmax and the attention-weighted sum run from registers with
// shfl_xor butterflies (xor16/32 over c-groups, xor1/2 over s) -> cost read
// from HBM exactly once, 16KB issued in one burst per wave, no barriers in the
// stream. The two 64x64 matvecs stay block-cooperative (16 points/block);
// w_k and w_v^T time-share one LDS buffer. Grid = 4096 blocks = 4 generations
// -> cross-generation overlap of matvec phases with streaming.
__global__ __launch_bounds__(256, 4) void pt_attn_kernel(
    const float* __restrict__ xyz,     // [B,3,N]
    const float* __restrict__ nxyz,    // [B,3,N,S]
    const float* __restrict__ point,   // [B,C,N]
    const float* __restrict__ cost,    // [B,C,N,S]
    const float* __restrict__ w_k,     // [C,C]
    const float* __restrict__ w_v,     // [C,C]
    const float* __restrict__ w_pos,   // [C,4]
    const float* __restrict__ b_pos,   // [C]
    float* __restrict__ out)           // [B,C,N]
{
    __shared__ float wmat[64][68];  // w_k[o][c]; after bar2: w_v^T[c][o]
    __shared__ float ptq[64][16];   // point tile * QSCALE, [o][nl]
    __shared__ float qp[16][68];    // qp[nl][c] = (W_k^T q)[c][n]
    __shared__ float wpb[5][65];    // w_pos^T[j][c] (j<4); b_pos[c] (j=4)
    __shared__ float qg[5][16];     // geometry coefs per point
    __shared__ float linit[4][64];  // per-wave logit init [w][n*16+s]
    __shared__ float wc[16][68];    // wc[nl][c] = sum_s attn*cost

    const int t  = threadIdx.x;
    const int b  = blockIdx.x >> 10;          // 1024 tiles per batch
    const int n0 = (blockIdx.x & 1023) << 4;  // 16 points per block

    const float* point_b = point + (size_t)b * NCH * NPTS;
    const float* cost_b  = cost  + (size_t)b * NCH * NPTS * NS;
    const float* xyz_b   = xyz   + (size_t)b * 3 * NPTS;
    const float* nxyz_b  = nxyz  + (size_t)b * 3 * NPTS * NS;
    float*       out_b   = out   + (size_t)b * NCH * NPTS;

    const int w    = __builtin_amdgcn_readfirstlane(t >> 6);  // wave 0..3
    const int lane = t & 63;

    // ---- region 0: stage w_k, scaled point tile, w_pos^T/b_pos ----
#pragma unroll
    for (int i = 0; i < 16; ++i) {
        int idx = t + i * 256;                 // wave reads one 64-float row
        wmat[idx >> 6][idx & 63] = w_k[idx];   // write banks (4o+c)%32: 2-way
    }
#pragma unroll
    for (int i = 0; i < 4; ++i) {
        int idx = t + i * 256;
        ptq[idx >> 4][idx & 15] = point_b[(idx >> 4) * NPTS + n0 + (idx & 15)] * QSCALE;
    }
    wpb[t & 3][t >> 2] = w_pos[t];             // [C,4] -> [j][c]
    if (t < 64) wpb[4][t] = b_pos[t];
    __syncthreads();

    // ---- region 1: qp[nl][c] = sum_o w_k[o][c] * ptq[o][nl] ----
    {
        const int nl = t & 15, cg = t >> 4;    // cg 0..15 -> c = cg*4..+3
        float a0 = 0.f, a1 = 0.f, a2 = 0.f, a3 = 0.f;
#pragma unroll 8
        for (int o = 0; o < NCH; ++o) {
            float pvv = ptq[o][nl];                          // 16 addrs, 4-way bcast
            float4 wk = *(const float4*)&wmat[o][cg * 4];    // b128, conflict-free
            a0 = fmaf(wk.x, pvv, a0);
            a1 = fmaf(wk.y, pvv, a1);
            a2 = fmaf(wk.z, pvv, a2);
            a3 = fmaf(wk.w, pvv, a3);
        }
        float4 r; r.x = a0; r.y = a1; r.z = a2; r.w = a3;
        *(float4*)&qp[nl][cg * 4] = r;
    }
    __syncthreads();

    // ---- region 2: qg (t<80) + stage w_v^T into wmat (w_k dead now) ----
    if (t < 80) {
        const int j = t >> 4, nl = t & 15;     // j 0..4
        float a = 0.f;
#pragma unroll 8
        for (int c = 0; c < NCH; ++c)
            a = fmaf(qp[nl][c], wpb[j][c], a); // wpb pad 65 -> conflict-free
        qg[j][nl] = a;                         // qg[4] = qp . b_pos
    }
#pragma unroll
    for (int i = 0; i < 16; ++i) {
        int idx = t + i * 256;
        wmat[idx & 63][idx >> 6] = w_v[idx];   // transposed store: w_v^T[c][o]
    }                                          // (8-way write conflict, one-time)
    __syncthreads();

    // ================= stream phase: per-wave, no barriers =================
    const int n0w = n0 + (w << 2);
    const int c2  = lane >> 4;         // c-group 0..3
    const int nn  = (lane >> 2) & 3;   // point-in-wave 0..3
    const int s4  = lane & 3;          // s-quad 0..3
    const int gn  = lane >> 4;         // geometry role: n 0..3
    const int gs  = lane & 15;         // geometry role: s 0..15

    // geometry loads FIRST so the cost burst behind them doesn't have to
    // drain (FIFO vmcnt) before the geometry math starts
    float gx0 = xyz_b[0 * NPTS + n0w + gn];
    float gx1 = xyz_b[1 * NPTS + n0w + gn];
    float gx2 = xyz_b[2 * NPTS + n0w + gn];
    float ga0 = nxyz_b[(size_t)(0 * NPTS + n0w + gn) * NS + gs];  // 256B runs
    float ga1 = nxyz_b[(size_t)(1 * NPTS + n0w + gn) * NS + gs];
    float ga2 = nxyz_b[(size_t)(2 * NPTS + n0w + gn) * NS + gs];

    // the wave's whole cost tile: 16 x dwordx4 = 16KB, all in flight at once.
    // Per instruction: 4 runs of 256B (full cache lines) at 1MB stride.
    const float4* cbase = (const float4*)(cost_b + (size_t)(n0w + nn) * NS) + s4;
    float4 cr[16];
#pragma unroll
    for (int g = 0; g < 16; ++g)
        cr[g] = cbase[(size_t)(g * 4 + c2) * NPTS * 4];

    // logit geometry init, bounced through LDS into the (c2,nn,s4) layout.
    // Same-wave LDS write->read: DS ops are in-order per wave.
    {
        float t0 = gx0 - ga0, t1 = gx1 - ga1, t2 = gx2 - ga2;
        float nr = sqrtf(fmaf(t0, t0, fmaf(t1, t1, t2 * t2)));
        int nlg = (w << 2) + gn;
        float li = fmaf(qg[0][nlg], t0, fmaf(qg[1][nlg], t1,
                   fmaf(qg[2][nlg], t2, fmaf(qg[3][nlg], nr, qg[4][nlg]))));
        linit[w][lane] = li;
    }
    float4 lg = *(const float4*)&linit[w][nn * 16 + s4 * 4];
    if (c2 != 0) { lg.x = 0.f; lg.y = 0.f; lg.z = 0.f; lg.w = 0.f; }  // add once

    // logits: this lane's 16 c's (c = g*4+c2) for its (n, s-quad)
    const int nl = (w << 2) + nn;
#pragma unroll
    for (int g = 0; g < 16; ++g) {
        float qv = qp[nl][g * 4 + c2];         // 16 banks, 4-way bcast
        lg.x = fmaf(qv, cr[g].x, lg.x);
        lg.y = fmaf(qv, cr[g].y, lg.y);
        lg.z = fmaf(qv, cr[g].z, lg.z);
        lg.w = fmaf(qv, cr[g].w, lg.w);
    }
    // reduce over c-groups (lane bits 4-5)
    lg.x += __shfl_xor(lg.x, 16); lg.y += __shfl_xor(lg.y, 16);
    lg.z += __shfl_xor(lg.z, 16); lg.w += __shfl_xor(lg.w, 16);
    lg.x += __shfl_xor(lg.x, 32); lg.y += __shfl_xor(lg.y, 32);
    lg.z += __shfl_xor(lg.z, 32); lg.w += __shfl_xor(lg.w, 32);

    // softmax over S=16: 4 in-lane x 4 lanes (bits 0-1)
    float m = fmaxf(fmaxf(lg.x, lg.y), fmaxf(lg.z, lg.w));
    m = fmaxf(m, __shfl_xor(m, 1));
    m = fmaxf(m, __shfl_xor(m, 2));
    float4 at;
    at.x = __expf(lg.x - m); at.y = __expf(lg.y - m);
    at.z = __expf(lg.z - m); at.w = __expf(lg.w - m);
    float Z = at.x + at.y + at.z + at.w;
    Z += __shfl_xor(Z, 1);
    Z += __shfl_xor(Z, 2);
    float rz = 1.f / Z;
    at.x *= rz; at.y *= rz; at.z *= rz; at.w *= rz;

    // weighted value sum, still from registers (cost's second use)
    float pv[16];
#pragma unroll
    for (int g = 0; g < 16; ++g) {
        float p = fmaf(at.x, cr[g].x, fmaf(at.y, cr[g].y,
                  fmaf(at.z, cr[g].z, at.w * cr[g].w)));
        p += __shfl_xor(p, 1);
        p += __shfl_xor(p, 2);
        pv[g] = p;
    }
    if (s4 == 0) {                              // 16 lanes, banks (4nl+4g+c2): free
#pragma unroll
        for (int g = 0; g < 16; ++g)
            wc[nl][g * 4 + c2] = pv[g];
    }
    __syncthreads();

    // ---- phase E: out[o][n] = sum_c w_v[o][c] * wc[c][n] ----
    {
        const int og = t >> 4, nlo = t & 15;
        float a0 = 0.f, a1 = 0.f, a2 = 0.f, a3 = 0.f;
#pragma unroll 8
        for (int c = 0; c < NCH; ++c) {
            float wcv = wc[nlo][c];                          // 2-way bcast read
            float4 wv = *(const float4*)&wmat[c][og * 4];    // w_v^T, b128, free
            a0 = fmaf(wv.x, wcv, a0);
            a1 = fmaf(wv.y, wcv, a1);
            a2 = fmaf(wv.z, wcv, a2);
            a3 = fmaf(wv.w, wcv, a3);
        }
        float* op = out_b + (size_t)(og * 4) * NPTS + n0 + nlo;
        op[0]        = a0;
        op[NPTS]     = a1;
        op[2 * NPTS] = a2;
        op[3 * NPTS] = a3;
    }
}

extern "C" void kernel_launch(void* const* d_in, const int* in_sizes, int n_in,
                              void* d_out, int out_size, void* d_ws, size_t ws_size,
                              hipStream_t stream) {
    const float* xyz   = (const float*)d_in[0];
    const float* nxyz  = (const float*)d_in[1];
    const float* point = (const float*)d_in[2];
    // d_in[3] = neighbor_points: unused by the reference computation
    const float* cost  = (const float*)d_in[4];
    const float* w_k   = (const float*)d_in[5];
    const float* w_v   = (const float*)d_in[6];
    const float* w_pos = (const float*)d_in[7];
    const float* b_pos = (const float*)d_in[8];
    float* outp = (float*)d_out;

    dim3 grid(4096), block(256);
    hipLaunchKernelGGL(pt_attn_kernel, grid, block, 0, stream,
                       xyz, nxyz, point, cost, w_k, w_v, w_pos, b_pos, outp);
}